// Round 4
// baseline (1236.169 us; speedup 1.0000x reference)
//
#include <hip/hip_runtime.h>
#include <stdint.h>

typedef __attribute__((ext_vector_type(8))) short bf16x8;
typedef __attribute__((ext_vector_type(4))) float f32x4;

__device__ __forceinline__ ushort f2bf(float f) {
  union { float f; uint32_t u; } v; v.f = f;
  return (ushort)((v.u + 0x7FFFu + ((v.u >> 16) & 1u)) >> 16);
}

__device__ __forceinline__ void load_lds16(const void* g, void* l) {
  __builtin_amdgcn_global_load_lds(
      (const __attribute__((address_space(1))) void*)g,
      (__attribute__((address_space(3))) void*)l, 16, 0, 0);
}

// ---- convert x (f32) -> bf16 ----
__global__ void cvt_bf16_kernel(const float4* __restrict__ x, ushort4* __restrict__ o, int n4) {
  int i = blockIdx.x * blockDim.x + threadIdx.x;
  int stride = gridDim.x * blockDim.x;
  for (; i < n4; i += stride) {
    float4 v = x[i];
    o[i] = make_ushort4(f2bf(v.x), f2bf(v.y), f2bf(v.z), f2bf(v.w));
  }
}

// ---- slice-partitioned W^T materialization (unchanged) ----
template <int A, int B, int CC, int M, int K, int S>
__global__ __launch_bounds__(256) void mat_slice_kernel(
    const float* __restrict__ t, ushort* __restrict__ wt, int n0, int nc, int lo) {
  const int w = threadIdx.x >> 6, lane = threadIdx.x & 63;
  const int nrel = blockIdx.x * 4 + w;
  if (nrel >= nc) return;
  const int n = n0 + nrel;
  const int offs = (int)(((unsigned)((long)n * B + CC)) & (unsigned)(M - 1));
  constexpr int J = (int)(((long)(K - 1) * A + (M - 1)) / M) + 1;
  constexpr int BIAS = 1024;
  ushort* wrow = wt + (size_t)nrel * K;
#pragma unroll 1
  for (int j = 0; j < J; ++j) {
    const int base = j * M + lo - offs;
    int kL = (int)((unsigned)(base + A * BIAS + A - 1) / (unsigned)A) - BIAS;
    int kU = (int)((unsigned)(base + S + A * BIAS + A - 1) / (unsigned)A) - BIAS;
    if (kL < 0) kL = 0;
    if (kU > K) kU = K;
    const int k = kL + lane;
    if (k < kU) {
      const int idx = k * A + offs - j * M;
      wrow[k] = f2bf(t[idx]);
    }
  }
}

// ---- 128x128 2-phase GEMM (layers 0/1, unchanged) ----
template <bool RELU_BF16, bool F32OUT>
__global__ __launch_bounds__(256) void gemm_bt(
    const ushort* __restrict__ Ag, const ushort* __restrict__ Bg,
    float* __restrict__ Cf, ushort* __restrict__ Ch,
    int K, int ldc, int colbase) {
  __shared__ ushort lA[128 * 64];
  __shared__ ushort lB[128 * 64];
  const int tid = threadIdx.x;
  const int w = tid >> 6, lane = tid & 63;
  const int mt = blockIdx.x & 15, nt = blockIdx.x >> 4;
  const int m0 = mt * 128, n0 = nt * 128;
  const int wm = (w >> 1) * 64, wn = (w & 1) * 64;

  f32x4 acc[4][4] = {};
  const int e0 = w * 512 + lane * 8;
  const ushort* Abase = Ag + (size_t)m0 * K;
  const ushort* Bbase = Bg + (size_t)n0 * K;

  for (int k0 = 0; k0 < K; k0 += 64) {
#pragma unroll
    for (int q = 0; q < 4; ++q) {
      int e = e0 + q * 2048;
      int row = e >> 6, col = e & 63;
      load_lds16(Abase + (size_t)row * K + (k0 + col), &lA[q * 2048 + w * 512]);
    }
#pragma unroll
    for (int q = 0; q < 4; ++q) {
      int e = e0 + q * 2048;
      int row = e >> 6, col = e & 63;
      load_lds16(Bbase + (size_t)row * K + (k0 + col), &lB[q * 2048 + w * 512]);
    }
    __syncthreads();

#pragma unroll
    for (int kk = 0; kk < 2; ++kk) {
      const int ko = kk * 32 + (lane >> 4) * 8;
      bf16x8 af[4], bfr[4];
#pragma unroll
      for (int i = 0; i < 4; ++i)
        af[i] = *(const bf16x8*)&lA[(wm + i * 16 + (lane & 15)) * 64 + ko];
#pragma unroll
      for (int i = 0; i < 4; ++i)
        bfr[i] = *(const bf16x8*)&lB[(wn + i * 16 + (lane & 15)) * 64 + ko];
#pragma unroll
      for (int mi = 0; mi < 4; ++mi)
#pragma unroll
        for (int ni = 0; ni < 4; ++ni)
          acc[mi][ni] = __builtin_amdgcn_mfma_f32_16x16x32_bf16(af[mi], bfr[ni], acc[mi][ni], 0, 0, 0);
    }
    __syncthreads();
  }

  const int fr = lane & 15, fq = lane >> 4;
#pragma unroll
  for (int mi = 0; mi < 4; ++mi)
#pragma unroll
    for (int ni = 0; ni < 4; ++ni)
#pragma unroll
      for (int e = 0; e < 4; ++e) {
        int row = m0 + wm + mi * 16 + fq * 4 + e;
        int col = colbase + n0 + wn + ni * 16 + fr;
        float v = acc[mi][ni][e];
        if (F32OUT) {
          Cf[(size_t)row * ldc + col] = v;
        } else {
          if (RELU_BF16) v = v > 0.0f ? v : 0.0f;
          Ch[(size_t)row * ldc + col] = f2bf(v);
        }
      }
}

// ==== 256x256 8-wave 4-phase counted-vmcnt GEMM, f32 out ====
// R3 change: MFMA16 re-ordered k-half OUTERMOST so consecutive MFMAs never
// write the same accumulator (dependent distance 8, was 1).
__device__ __forceinline__ void stq(const ushort* src, size_t qstep, int q,
                                    ushort* dstbase, int tid) {
  load_lds16(src + (size_t)q * qstep, dstbase + q * 4096 + tid * 8);
}

__global__ __launch_bounds__(512, 2) void gemm256(
    const ushort* __restrict__ Ag, const ushort* __restrict__ Bg,
    float* __restrict__ Cf, int K, int ldc, int colbase, int mtiles) {
  __shared__ alignas(16) ushort lds[2 * 2 * 16384];  // 128 KiB
  const int tid = threadIdx.x;
  const int lane = tid & 63, w = tid >> 6;
  const int wr = w >> 2, wc = w & 3;
  const int fr = lane & 15, fq = lane >> 4, l7 = lane & 7;

  // bijective XCD swizzle (m204)
  const int nwg = (int)gridDim.x, bid = (int)blockIdx.x;
  const int q8 = nwg >> 3, r8 = nwg & 7;
  const int xcd = bid & 7, ix = bid >> 3;
  const int swz = (xcd < r8 ? xcd * (q8 + 1) : r8 * (q8 + 1) + (xcd - r8) * q8) + ix;
  const int m0 = (swz % mtiles) * 256;
  const int n0 = (swz / mtiles) * 256;

  const int rowq = tid >> 3;
  const int cswz = ((tid & 7) ^ (rowq & 7)) * 8;
  const ushort* sA = Ag + (size_t)(m0 + rowq) * K + cswz;
  const ushort* sB = Bg + (size_t)(n0 + rowq) * K + cswz;
  const size_t qstep = (size_t)64 * (size_t)K;

  const int au0 = ((0 * 4 + fq) ^ l7) * 8;
  const int au1 = ((1 * 4 + fq) ^ l7) * 8;
  const int abase = (wr * 16 + fr) * 64;
  const int bbase = (wc * 64 + fr) * 64;

  f32x4 acc[8][4] = {};
  bf16x8 aF[2][2], bF[4][2];

  // prologue: stage tile 0 into buf 0 (FIFO: B0..B3, A0..A3)
  {
    ushort* nAv = lds;
    ushort* nBv = lds + 16384;
    stq(sB, qstep, 0, nBv, tid); stq(sB, qstep, 1, nBv, tid);
    stq(sB, qstep, 2, nBv, tid); stq(sB, qstep, 3, nBv, tid);
    stq(sA, qstep, 0, nAv, tid); stq(sA, qstep, 1, nAv, tid);
    stq(sA, qstep, 2, nAv, tid); stq(sA, qstep, 3, nAv, tid);
    sA += 64; sB += 64;
  }
  asm volatile("s_waitcnt vmcnt(3)" ::: "memory");
  __builtin_amdgcn_s_barrier();

#define RDA(P)                                                      \
  aF[0][0] = *(const bf16x8*)(bAv + abase + (2 * (P)) * 2048 + au0); \
  aF[0][1] = *(const bf16x8*)(bAv + abase + (2 * (P)) * 2048 + au1); \
  aF[1][0] = *(const bf16x8*)(bAv + abase + (2 * (P) + 1) * 2048 + au0); \
  aF[1][1] = *(const bf16x8*)(bAv + abase + (2 * (P) + 1) * 2048 + au1);

// k-half outermost: all 8 accumulators touched before any is revisited.
#define MFMA16(P)                                                   \
  __builtin_amdgcn_s_setprio(1);                                    \
  _Pragma("unroll")                                                 \
  for (int kk = 0; kk < 2; ++kk) {                                  \
    _Pragma("unroll")                                               \
    for (int mi2 = 0; mi2 < 2; ++mi2) {                             \
      _Pragma("unroll")                                             \
      for (int nj = 0; nj < 4; ++nj)                                \
        acc[2 * (P) + mi2][nj] = __builtin_amdgcn_mfma_f32_16x16x32_bf16( \
            aF[mi2][kk], bF[nj][kk], acc[2 * (P) + mi2][nj], 0, 0, 0); \
    }                                                               \
  }                                                                 \
  __builtin_amdgcn_s_setprio(0);

  const int T = K >> 6;
#pragma unroll 1
  for (int t = 0; t < T; ++t) {
    const int b = t & 1;
    ushort* bAv = lds + b * 32768;
    ushort* bBv = bAv + 16384;
    ushort* nAv = lds + (b ^ 1) * 32768;
    ushort* nBv = nAv + 16384;
    const bool pre = (t + 1 < T);

    // phase 0: read A-quarter 0 + all B; stage Bq0,Bq1
    RDA(0);
#pragma unroll
    for (int nj = 0; nj < 4; ++nj) {
      bF[nj][0] = *(const bf16x8*)(bBv + bbase + nj * 1024 + au0);
      bF[nj][1] = *(const bf16x8*)(bBv + bbase + nj * 1024 + au1);
    }
    if (pre) { stq(sB, qstep, 0, nBv, tid); stq(sB, qstep, 1, nBv, tid);
               asm volatile("s_waitcnt vmcnt(4)" ::: "memory"); }
    else     { asm volatile("s_waitcnt vmcnt(2)" ::: "memory"); }
    __builtin_amdgcn_s_barrier();
    MFMA16(0);
    __builtin_amdgcn_s_barrier();

    // phase 1: A-quarter 1; stage Bq2,Bq3
    RDA(1);
    if (pre) { stq(sB, qstep, 2, nBv, tid); stq(sB, qstep, 3, nBv, tid);
               asm volatile("s_waitcnt vmcnt(5)" ::: "memory"); }
    else     { asm volatile("s_waitcnt vmcnt(1)" ::: "memory"); }
    __builtin_amdgcn_s_barrier();
    MFMA16(1);
    __builtin_amdgcn_s_barrier();

    // phase 2: A-quarter 2; stage Aq0,Aq1
    RDA(2);
    if (pre) { stq(sA, qstep, 0, nAv, tid); stq(sA, qstep, 1, nAv, tid);
               asm volatile("s_waitcnt vmcnt(6)" ::: "memory"); }
    else     { asm volatile("s_waitcnt vmcnt(0)" ::: "memory"); }
    __builtin_amdgcn_s_barrier();
    MFMA16(2);
    __builtin_amdgcn_s_barrier();

    // phase 3: A-quarter 3; stage Aq2,Aq3
    RDA(3);
    if (pre) { stq(sA, qstep, 2, nAv, tid); stq(sA, qstep, 3, nAv, tid);
               asm volatile("s_waitcnt vmcnt(3)" ::: "memory"); }
    __builtin_amdgcn_s_barrier();
    MFMA16(3);
    __builtin_amdgcn_s_barrier();

    if (pre) { sA += 64; sB += 64; }
  }
#undef RDA
#undef MFMA16

  // epilogue: C/D map col=lane&15, row=(lane>>4)*4+e (m89)
#pragma unroll
  for (int mi = 0; mi < 8; ++mi)
#pragma unroll
    for (int nj = 0; nj < 4; ++nj)
#pragma unroll
      for (int e = 0; e < 4; ++e) {
        int row = m0 + wr * 16 + mi * 32 + fq * 4 + e;
        int col = colbase + n0 + wc * 64 + nj * 16 + fr;
        Cf[(size_t)row * ldc + col] = acc[mi][nj][e];
      }
}

template <int A, int B, int CC, int M, int K>
static void run_layer(const ushort* Ain, const float* tbl, ushort* hOut, float* fOut,
                      int N, int ldc, ushort* wb, size_t avail, hipStream_t stream) {
  constexpr int S = 1 << 19;
  long ncmax = (long)(avail / (size_t)((size_t)K * 2));
  ncmax = (ncmax / 128) * 128;
  if (ncmax > N) ncmax = N;
  if (ncmax < 128) ncmax = 128;
  for (int n0 = 0; n0 < N; n0 += (int)ncmax) {
    int nc = (N - n0 < (int)ncmax) ? (N - n0) : (int)ncmax;
    dim3 gm((unsigned)((nc + 3) / 4));
    for (int lo = 0; lo < M; lo += S)
      hipLaunchKernelGGL((mat_slice_kernel<A, B, CC, M, K, S>), gm, dim3(256), 0, stream,
                         tbl, wb, n0, nc, lo);
    dim3 g((unsigned)((nc / 128) * 16));
    if (fOut)
      hipLaunchKernelGGL((gemm_bt<false, true>), g, dim3(256), 0, stream,
                         Ain, wb, fOut, (ushort*)nullptr, K, ldc, n0);
    else
      hipLaunchKernelGGL((gemm_bt<true, false>), g, dim3(256), 0, stream,
                         Ain, wb, (float*)nullptr, hOut, K, ldc, n0);
  }
}

extern "C" void kernel_launch(void* const* d_in, const int* in_sizes, int n_in,
                              void* d_out, int out_size, void* d_ws, size_t ws_size,
                              hipStream_t stream) {
  const float* x   = (const float*)d_in[0];
  const float* hw0 = (const float*)d_in[1];
  const float* hw1 = (const float*)d_in[2];
  const float* hw2 = (const float*)d_in[3];
  float* out = (float*)d_out;
  uint8_t* ws = (uint8_t*)d_ws;

  ushort* xb = (ushort*)(ws + 0);                     // 2048x1024 bf16  (4 MB)
  ushort* h1 = (ushort*)(ws + ((size_t)4 << 20));     // 2048x4096 bf16 (16 MB)
  ushort* h2 = (ushort*)(ws + ((size_t)20 << 20));    // 2048x4096 bf16 (16 MB)
  ushort* wb = (ushort*)(ws + ((size_t)36 << 20));    // W^T chunk buffer
  size_t avail = ws_size > ((size_t)36 << 20) ? ws_size - ((size_t)36 << 20)
                                              : (size_t)(128 * 4096 * 2);

  hipLaunchKernelGGL(cvt_bf16_kernel, dim3(1024), dim3(256), 0, stream,
                     (const float4*)x, (ushort4*)xb, 2048 * 1024 / 4);

  // layer 0: [2048,1024] @ [1024,4096], relu -> h1 (bf16)  [128^2 path]
  run_layer<9973, 31013, 557, 1 << 20, 1024>(xb, hw0, h1, nullptr, 4096, 4096, wb, avail, stream);
  // layer 1: [2048,4096] @ [4096,4096], relu -> h2 (bf16)  [128^2 path]
  run_layer<10007, 31019, 563, 1 << 20, 4096>(h1, hw1, h2, nullptr, 4096, 4096, wb, avail, stream);

  // layer 2: [2048,4096] @ [4096,32000] -> out (f32)  [256^2 8-phase path]
  {
    constexpr int K = 4096, N = 32000, S = 1 << 19, M = 1 << 22;
    long ncmax = (long)(avail / (size_t)((size_t)K * 2));
    ncmax = (ncmax / 256) * 256;
    if (ncmax > N) ncmax = N;
    if (ncmax < 256) ncmax = 256;
    for (int n0 = 0; n0 < N; n0 += (int)ncmax) {
      int nc = (N - n0 < (int)ncmax) ? (N - n0) : (int)ncmax;
      dim3 gm((unsigned)((nc + 3) / 4));
      for (int lo = 0; lo < M; lo += S)
        hipLaunchKernelGGL((mat_slice_kernel<10039, 31039, 569, M, K, S>), gm, dim3(256), 0, stream,
                           hw2, wb, n0, nc, lo);
      hipLaunchKernelGGL(gemm256, dim3((unsigned)((nc / 256) * 8)), dim3(512), 0, stream,
                         h2, wb, out, K, N, n0, 8);
    }
  }
}

// Round 5
// 1218.956 us; speedup vs baseline: 1.0141x; 1.0141x over previous
//
#include <hip/hip_runtime.h>
#include <stdint.h>

typedef __attribute__((ext_vector_type(8))) short bf16x8;
typedef __attribute__((ext_vector_type(4))) float f32x4;

__device__ __forceinline__ ushort f2bf(float f) {
  union { float f; uint32_t u; } v; v.f = f;
  return (ushort)((v.u + 0x7FFFu + ((v.u >> 16) & 1u)) >> 16);
}

__device__ __forceinline__ void load_lds16(const void* g, void* l) {
  __builtin_amdgcn_global_load_lds(
      (const __attribute__((address_space(1))) void*)g,
      (__attribute__((address_space(3))) void*)l, 16, 0, 0);
}

// ---- convert x (f32) -> bf16 ----
__global__ void cvt_bf16_kernel(const float4* __restrict__ x, ushort4* __restrict__ o, int n4) {
  int i = blockIdx.x * blockDim.x + threadIdx.x;
  int stride = gridDim.x * blockDim.x;
  for (; i < n4; i += stride) {
    float4 v = x[i];
    o[i] = make_ushort4(f2bf(v.x), f2bf(v.y), f2bf(v.z), f2bf(v.w));
  }
}

// ---- slice-partitioned W^T materialization (unchanged) ----
template <int A, int B, int CC, int M, int K, int S>
__global__ __launch_bounds__(256) void mat_slice_kernel(
    const float* __restrict__ t, ushort* __restrict__ wt, int n0, int nc, int lo) {
  const int w = threadIdx.x >> 6, lane = threadIdx.x & 63;
  const int nrel = blockIdx.x * 4 + w;
  if (nrel >= nc) return;
  const int n = n0 + nrel;
  const int offs = (int)(((unsigned)((long)n * B + CC)) & (unsigned)(M - 1));
  constexpr int J = (int)(((long)(K - 1) * A + (M - 1)) / M) + 1;
  constexpr int BIAS = 1024;
  ushort* wrow = wt + (size_t)nrel * K;
#pragma unroll 1
  for (int j = 0; j < J; ++j) {
    const int base = j * M + lo - offs;
    int kL = (int)((unsigned)(base + A * BIAS + A - 1) / (unsigned)A) - BIAS;
    int kU = (int)((unsigned)(base + S + A * BIAS + A - 1) / (unsigned)A) - BIAS;
    if (kL < 0) kL = 0;
    if (kU > K) kU = K;
    const int k = kL + lane;
    if (k < kU) {
      const int idx = k * A + offs - j * M;
      wrow[k] = f2bf(t[idx]);
    }
  }
}

// ---- 128x128 2-phase GEMM (layers 0/1, unchanged) ----
template <bool RELU_BF16, bool F32OUT>
__global__ __launch_bounds__(256) void gemm_bt(
    const ushort* __restrict__ Ag, const ushort* __restrict__ Bg,
    float* __restrict__ Cf, ushort* __restrict__ Ch,
    int K, int ldc, int colbase) {
  __shared__ ushort lA[128 * 64];
  __shared__ ushort lB[128 * 64];
  const int tid = threadIdx.x;
  const int w = tid >> 6, lane = tid & 63;
  const int mt = blockIdx.x & 15, nt = blockIdx.x >> 4;
  const int m0 = mt * 128, n0 = nt * 128;
  const int wm = (w >> 1) * 64, wn = (w & 1) * 64;

  f32x4 acc[4][4] = {};
  const int e0 = w * 512 + lane * 8;
  const ushort* Abase = Ag + (size_t)m0 * K;
  const ushort* Bbase = Bg + (size_t)n0 * K;

  for (int k0 = 0; k0 < K; k0 += 64) {
#pragma unroll
    for (int q = 0; q < 4; ++q) {
      int e = e0 + q * 2048;
      int row = e >> 6, col = e & 63;
      load_lds16(Abase + (size_t)row * K + (k0 + col), &lA[q * 2048 + w * 512]);
    }
#pragma unroll
    for (int q = 0; q < 4; ++q) {
      int e = e0 + q * 2048;
      int row = e >> 6, col = e & 63;
      load_lds16(Bbase + (size_t)row * K + (k0 + col), &lB[q * 2048 + w * 512]);
    }
    __syncthreads();

#pragma unroll
    for (int kk = 0; kk < 2; ++kk) {
      const int ko = kk * 32 + (lane >> 4) * 8;
      bf16x8 af[4], bfr[4];
#pragma unroll
      for (int i = 0; i < 4; ++i)
        af[i] = *(const bf16x8*)&lA[(wm + i * 16 + (lane & 15)) * 64 + ko];
#pragma unroll
      for (int i = 0; i < 4; ++i)
        bfr[i] = *(const bf16x8*)&lB[(wn + i * 16 + (lane & 15)) * 64 + ko];
#pragma unroll
      for (int mi = 0; mi < 4; ++mi)
#pragma unroll
        for (int ni = 0; ni < 4; ++ni)
          acc[mi][ni] = __builtin_amdgcn_mfma_f32_16x16x32_bf16(af[mi], bfr[ni], acc[mi][ni], 0, 0, 0);
    }
    __syncthreads();
  }

  const int fr = lane & 15, fq = lane >> 4;
#pragma unroll
  for (int mi = 0; mi < 4; ++mi)
#pragma unroll
    for (int ni = 0; ni < 4; ++ni)
#pragma unroll
      for (int e = 0; e < 4; ++e) {
        int row = m0 + wm + mi * 16 + fq * 4 + e;
        int col = colbase + n0 + wn + ni * 16 + fr;
        float v = acc[mi][ni][e];
        if (F32OUT) {
          Cf[(size_t)row * ldc + col] = v;
        } else {
          if (RELU_BF16) v = v > 0.0f ? v : 0.0f;
          Ch[(size_t)row * ldc + col] = f2bf(v);
        }
      }
}

// ==== 256x256 8-wave 4-phase counted-vmcnt GEMM, f32 out ====
// R4 change: B-fragment ds_reads moved from phase-0-top (same-phase use, 12-read
// cold spike before MFMA(0)) to phase-3-tail AFTER MFMA(3): they read next-tile
// B from nBv (landed per W3+barrier) into bF in place (dead after MFMA(3)),
// and complete under the following barrier/RDA/wait before MFMA(0) of t+1.
__device__ __forceinline__ void stq(const ushort* src, size_t qstep, int q,
                                    ushort* dstbase, int tid) {
  load_lds16(src + (size_t)q * qstep, dstbase + q * 4096 + tid * 8);
}

__global__ __launch_bounds__(512, 2) void gemm256(
    const ushort* __restrict__ Ag, const ushort* __restrict__ Bg,
    float* __restrict__ Cf, int K, int ldc, int colbase, int mtiles) {
  __shared__ alignas(16) ushort lds[2 * 2 * 16384];  // 128 KiB
  const int tid = threadIdx.x;
  const int lane = tid & 63, w = tid >> 6;
  const int wr = w >> 2, wc = w & 3;
  const int fr = lane & 15, fq = lane >> 4, l7 = lane & 7;

  // bijective XCD swizzle (m204)
  const int nwg = (int)gridDim.x, bid = (int)blockIdx.x;
  const int q8 = nwg >> 3, r8 = nwg & 7;
  const int xcd = bid & 7, ix = bid >> 3;
  const int swz = (xcd < r8 ? xcd * (q8 + 1) : r8 * (q8 + 1) + (xcd - r8) * q8) + ix;
  const int m0 = (swz % mtiles) * 256;
  const int n0 = (swz / mtiles) * 256;

  const int rowq = tid >> 3;
  const int cswz = ((tid & 7) ^ (rowq & 7)) * 8;
  const ushort* sA = Ag + (size_t)(m0 + rowq) * K + cswz;
  const ushort* sB = Bg + (size_t)(n0 + rowq) * K + cswz;
  const size_t qstep = (size_t)64 * (size_t)K;

  const int au0 = ((0 * 4 + fq) ^ l7) * 8;
  const int au1 = ((1 * 4 + fq) ^ l7) * 8;
  const int abase = (wr * 16 + fr) * 64;
  const int bbase = (wc * 64 + fr) * 64;

  f32x4 acc[8][4] = {};
  bf16x8 aF[2][2], bF[4][2];

  // prologue: stage tile 0 into buf 0 (FIFO: B0..B3, A0..A3)
  {
    ushort* nAv = lds;
    ushort* nBv = lds + 16384;
    stq(sB, qstep, 0, nBv, tid); stq(sB, qstep, 1, nBv, tid);
    stq(sB, qstep, 2, nBv, tid); stq(sB, qstep, 3, nBv, tid);
    stq(sA, qstep, 0, nAv, tid); stq(sA, qstep, 1, nAv, tid);
    stq(sA, qstep, 2, nAv, tid); stq(sA, qstep, 3, nAv, tid);
    sA += 64; sB += 64;
  }
  asm volatile("s_waitcnt vmcnt(3)" ::: "memory");
  __builtin_amdgcn_s_barrier();
  // preload B fragments for tile 0 (B0..B3 landed: vmcnt(3) left only A1..A3)
  {
    const ushort* pB = lds + 16384;
#pragma unroll
    for (int nj = 0; nj < 4; ++nj) {
      bF[nj][0] = *(const bf16x8*)(pB + bbase + nj * 1024 + au0);
      bF[nj][1] = *(const bf16x8*)(pB + bbase + nj * 1024 + au1);
    }
  }

#define RDA(P)                                                      \
  aF[0][0] = *(const bf16x8*)(bAv + abase + (2 * (P)) * 2048 + au0); \
  aF[0][1] = *(const bf16x8*)(bAv + abase + (2 * (P)) * 2048 + au1); \
  aF[1][0] = *(const bf16x8*)(bAv + abase + (2 * (P) + 1) * 2048 + au0); \
  aF[1][1] = *(const bf16x8*)(bAv + abase + (2 * (P) + 1) * 2048 + au1);

#define MFMA16(P)                                                   \
  __builtin_amdgcn_s_setprio(1);                                    \
  _Pragma("unroll")                                                 \
  for (int kk = 0; kk < 2; ++kk) {                                  \
    _Pragma("unroll")                                               \
    for (int mi2 = 0; mi2 < 2; ++mi2) {                             \
      _Pragma("unroll")                                             \
      for (int nj = 0; nj < 4; ++nj)                                \
        acc[2 * (P) + mi2][nj] = __builtin_amdgcn_mfma_f32_16x16x32_bf16( \
            aF[mi2][kk], bF[nj][kk], acc[2 * (P) + mi2][nj], 0, 0, 0); \
    }                                                               \
  }                                                                 \
  __builtin_amdgcn_s_setprio(0);

  const int T = K >> 6;
#pragma unroll 1
  for (int t = 0; t < T; ++t) {
    const int b = t & 1;
    ushort* bAv = lds + b * 32768;
    ushort* bBv = bAv + 16384;
    ushort* nAv = lds + (b ^ 1) * 32768;
    ushort* nBv = nAv + 16384;
    const bool pre = (t + 1 < T);
    (void)bBv;

    // phase 0: read A-quarter 0 (B frags already in regs); stage Bq0,Bq1
    RDA(0);
    if (pre) { stq(sB, qstep, 0, nBv, tid); stq(sB, qstep, 1, nBv, tid);
               asm volatile("s_waitcnt vmcnt(4)" ::: "memory"); }
    else     { asm volatile("s_waitcnt vmcnt(2)" ::: "memory"); }
    __builtin_amdgcn_s_barrier();
    MFMA16(0);
    __builtin_amdgcn_s_barrier();

    // phase 1: A-quarter 1; stage Bq2,Bq3
    RDA(1);
    if (pre) { stq(sB, qstep, 2, nBv, tid); stq(sB, qstep, 3, nBv, tid);
               asm volatile("s_waitcnt vmcnt(5)" ::: "memory"); }
    else     { asm volatile("s_waitcnt vmcnt(1)" ::: "memory"); }
    __builtin_amdgcn_s_barrier();
    MFMA16(1);
    __builtin_amdgcn_s_barrier();

    // phase 2: A-quarter 2; stage Aq0,Aq1
    RDA(2);
    if (pre) { stq(sA, qstep, 0, nAv, tid); stq(sA, qstep, 1, nAv, tid);
               asm volatile("s_waitcnt vmcnt(6)" ::: "memory"); }
    else     { asm volatile("s_waitcnt vmcnt(0)" ::: "memory"); }
    __builtin_amdgcn_s_barrier();
    MFMA16(2);
    __builtin_amdgcn_s_barrier();

    // phase 3: A-quarter 3; stage Aq2,Aq3; after MFMA(3), prefetch next-tile
    // B fragments from nBv into bF (in place; landed per W3+barrier).
    RDA(3);
    if (pre) { stq(sA, qstep, 2, nAv, tid); stq(sA, qstep, 3, nAv, tid);
               asm volatile("s_waitcnt vmcnt(3)" ::: "memory"); }
    __builtin_amdgcn_s_barrier();
    MFMA16(3);
    if (pre) {
#pragma unroll
      for (int nj = 0; nj < 4; ++nj) {
        bF[nj][0] = *(const bf16x8*)(nBv + bbase + nj * 1024 + au0);
        bF[nj][1] = *(const bf16x8*)(nBv + bbase + nj * 1024 + au1);
      }
    }
    __builtin_amdgcn_s_barrier();

    if (pre) { sA += 64; sB += 64; }
  }
#undef RDA
#undef MFMA16

  // epilogue: C/D map col=lane&15, row=(lane>>4)*4+e (m89)
#pragma unroll
  for (int mi = 0; mi < 8; ++mi)
#pragma unroll
    for (int nj = 0; nj < 4; ++nj)
#pragma unroll
      for (int e = 0; e < 4; ++e) {
        int row = m0 + wr * 16 + mi * 32 + fq * 4 + e;
        int col = colbase + n0 + wc * 64 + nj * 16 + fr;
        Cf[(size_t)row * ldc + col] = acc[mi][nj][e];
      }
}

template <int A, int B, int CC, int M, int K>
static void run_layer(const ushort* Ain, const float* tbl, ushort* hOut, float* fOut,
                      int N, int ldc, ushort* wb, size_t avail, hipStream_t stream) {
  constexpr int S = 1 << 19;
  long ncmax = (long)(avail / (size_t)((size_t)K * 2));
  ncmax = (ncmax / 128) * 128;
  if (ncmax > N) ncmax = N;
  if (ncmax < 128) ncmax = 128;
  for (int n0 = 0; n0 < N; n0 += (int)ncmax) {
    int nc = (N - n0 < (int)ncmax) ? (N - n0) : (int)ncmax;
    dim3 gm((unsigned)((nc + 3) / 4));
    for (int lo = 0; lo < M; lo += S)
      hipLaunchKernelGGL((mat_slice_kernel<A, B, CC, M, K, S>), gm, dim3(256), 0, stream,
                         tbl, wb, n0, nc, lo);
    dim3 g((unsigned)((nc / 128) * 16));
    if (fOut)
      hipLaunchKernelGGL((gemm_bt<false, true>), g, dim3(256), 0, stream,
                         Ain, wb, fOut, (ushort*)nullptr, K, ldc, n0);
    else
      hipLaunchKernelGGL((gemm_bt<true, false>), g, dim3(256), 0, stream,
                         Ain, wb, (float*)nullptr, hOut, K, ldc, n0);
  }
}

extern "C" void kernel_launch(void* const* d_in, const int* in_sizes, int n_in,
                              void* d_out, int out_size, void* d_ws, size_t ws_size,
                              hipStream_t stream) {
  const float* x   = (const float*)d_in[0];
  const float* hw0 = (const float*)d_in[1];
  const float* hw1 = (const float*)d_in[2];
  const float* hw2 = (const float*)d_in[3];
  float* out = (float*)d_out;
  uint8_t* ws = (uint8_t*)d_ws;

  ushort* xb = (ushort*)(ws + 0);                     // 2048x1024 bf16  (4 MB)
  ushort* h1 = (ushort*)(ws + ((size_t)4 << 20));     // 2048x4096 bf16 (16 MB)
  ushort* h2 = (ushort*)(ws + ((size_t)20 << 20));    // 2048x4096 bf16 (16 MB)
  ushort* wb = (ushort*)(ws + ((size_t)36 << 20));    // W^T chunk buffer
  size_t avail = ws_size > ((size_t)36 << 20) ? ws_size - ((size_t)36 << 20)
                                              : (size_t)(128 * 4096 * 2);

  hipLaunchKernelGGL(cvt_bf16_kernel, dim3(1024), dim3(256), 0, stream,
                     (const float4*)x, (ushort4*)xb, 2048 * 1024 / 4);

  // layer 0: [2048,1024] @ [1024,4096], relu -> h1 (bf16)  [128^2 path]
  run_layer<9973, 31013, 557, 1 << 20, 1024>(xb, hw0, h1, nullptr, 4096, 4096, wb, avail, stream);
  // layer 1: [2048,4096] @ [4096,4096], relu -> h2 (bf16)  [128^2 path]
  run_layer<10007, 31019, 563, 1 << 20, 4096>(h1, hw1, h2, nullptr, 4096, 4096, wb, avail, stream);

  // layer 2: [2048,4096] @ [4096,32000] -> out (f32)  [256^2 4-phase path]
  {
    constexpr int K = 4096, N = 32000, S = 1 << 19, M = 1 << 22;
    long ncmax = (long)(avail / (size_t)((size_t)K * 2));
    ncmax = (ncmax / 256) * 256;
    if (ncmax > N) ncmax = N;
    if (ncmax < 256) ncmax = 256;
    for (int n0 = 0; n0 < N; n0 += (int)ncmax) {
      int nc = (N - n0 < (int)ncmax) ? (N - n0) : (int)ncmax;
      dim3 gm((unsigned)((nc + 3) / 4));
      for (int lo = 0; lo < M; lo += S)
        hipLaunchKernelGGL((mat_slice_kernel<10039, 31039, 569, M, K, S>), gm, dim3(256), 0, stream,
                           hw2, wb, n0, nc, lo);
      hipLaunchKernelGGL(gemm256, dim3((unsigned)((nc / 256) * 8)), dim3(512), 0, stream,
                         h2, wb, out, K, N, n0, 8);
    }
  }
}

// Round 6
// 1206.981 us; speedup vs baseline: 1.0242x; 1.0099x over previous
//
#include <hip/hip_runtime.h>
#include <stdint.h>

typedef __attribute__((ext_vector_type(8))) short bf16x8;
typedef __attribute__((ext_vector_type(4))) float f32x4;

__device__ __forceinline__ ushort f2bf(float f) {
  union { float f; uint32_t u; } v; v.f = f;
  return (ushort)((v.u + 0x7FFFu + ((v.u >> 16) & 1u)) >> 16);
}

__device__ __forceinline__ void load_lds16(const void* g, void* l) {
  __builtin_amdgcn_global_load_lds(
      (const __attribute__((address_space(1))) void*)g,
      (__attribute__((address_space(3))) void*)l, 16, 0, 0);
}

// ---- convert x (f32) -> bf16 ----
__global__ void cvt_bf16_kernel(const float4* __restrict__ x, ushort4* __restrict__ o, int n4) {
  int i = blockIdx.x * blockDim.x + threadIdx.x;
  int stride = gridDim.x * blockDim.x;
  for (; i < n4; i += stride) {
    float4 v = x[i];
    o[i] = make_ushort4(f2bf(v.x), f2bf(v.y), f2bf(v.z), f2bf(v.w));
  }
}

// ---- slice-partitioned W^T materialization, ALL slices in one launch ----
// slice = blockIdx.x / bps (blocks dispatched in ascending order -> slices
// processed in temporal order -> live slice stays L2-resident).
template <int A, int B, int CC, int M, int K, int S>
__global__ __launch_bounds__(256) void mat_all_kernel(
    const float* __restrict__ t, ushort* __restrict__ wt, int n0, int nc, int bps) {
  const int slice = blockIdx.x / bps;
  const int blk = blockIdx.x - slice * bps;
  const int lo = slice * S;
  const int w = threadIdx.x >> 6, lane = threadIdx.x & 63;
  const int nrel = blk * 4 + w;
  if (nrel >= nc) return;
  const int n = n0 + nrel;
  const int offs = (int)(((unsigned)((long)n * B + CC)) & (unsigned)(M - 1));
  constexpr int J = (int)(((long)(K - 1) * A + (M - 1)) / M) + 1;
  constexpr int BIAS = 1024;
  ushort* wrow = wt + (size_t)nrel * K;
#pragma unroll 1
  for (int j = 0; j < J; ++j) {
    const int base = j * M + lo - offs;
    int kL = (int)((unsigned)(base + A * BIAS + A - 1) / (unsigned)A) - BIAS;
    int kU = (int)((unsigned)(base + S + A * BIAS + A - 1) / (unsigned)A) - BIAS;
    if (kL < 0) kL = 0;
    if (kU > K) kU = K;
    const int k = kL + lane;
    if (k < kU) {
      const int idx = k * A + offs - j * M;
      wrow[k] = f2bf(t[idx]);
    }
  }
}

// ==== 256x256 8-wave 4-phase counted-vmcnt GEMM ====
// Templated epilogue: F32OUT -> f32 store; else relu+bf16 store.
__device__ __forceinline__ void stq(const ushort* src, size_t qstep, int q,
                                    ushort* dstbase, int tid) {
  load_lds16(src + (size_t)q * qstep, dstbase + q * 4096 + tid * 8);
}

template <bool F32OUT>
__global__ __launch_bounds__(512, 2) void gemm256(
    const ushort* __restrict__ Ag, const ushort* __restrict__ Bg,
    float* __restrict__ Cf, ushort* __restrict__ Ch,
    int K, int ldc, int colbase, int mtiles) {
  __shared__ alignas(16) ushort lds[2 * 2 * 16384];  // 128 KiB
  const int tid = threadIdx.x;
  const int lane = tid & 63, w = tid >> 6;
  const int wr = w >> 2, wc = w & 3;
  const int fr = lane & 15, fq = lane >> 4, l7 = lane & 7;

  // bijective XCD swizzle (m204)
  const int nwg = (int)gridDim.x, bid = (int)blockIdx.x;
  const int q8 = nwg >> 3, r8 = nwg & 7;
  const int xcd = bid & 7, ix = bid >> 3;
  const int swz = (xcd < r8 ? xcd * (q8 + 1) : r8 * (q8 + 1) + (xcd - r8) * q8) + ix;
  const int m0 = (swz % mtiles) * 256;
  const int n0 = (swz / mtiles) * 256;

  const int rowq = tid >> 3;
  const int cswz = ((tid & 7) ^ (rowq & 7)) * 8;
  const ushort* sA = Ag + (size_t)(m0 + rowq) * K + cswz;
  const ushort* sB = Bg + (size_t)(n0 + rowq) * K + cswz;
  const size_t qstep = (size_t)64 * (size_t)K;

  const int au0 = ((0 * 4 + fq) ^ l7) * 8;
  const int au1 = ((1 * 4 + fq) ^ l7) * 8;
  const int abase = (wr * 16 + fr) * 64;
  const int bbase = (wc * 64 + fr) * 64;

  f32x4 acc[8][4] = {};
  bf16x8 aF[2][2], bF[4][2];

  // prologue: stage tile 0 into buf 0 (FIFO: B0..B3, A0..A3)
  {
    ushort* nAv = lds;
    ushort* nBv = lds + 16384;
    stq(sB, qstep, 0, nBv, tid); stq(sB, qstep, 1, nBv, tid);
    stq(sB, qstep, 2, nBv, tid); stq(sB, qstep, 3, nBv, tid);
    stq(sA, qstep, 0, nAv, tid); stq(sA, qstep, 1, nAv, tid);
    stq(sA, qstep, 2, nAv, tid); stq(sA, qstep, 3, nAv, tid);
    sA += 64; sB += 64;
  }
  asm volatile("s_waitcnt vmcnt(3)" ::: "memory");
  __builtin_amdgcn_s_barrier();
  // preload B fragments for tile 0 (B0..B3 landed: vmcnt(3) left only A1..A3)
  {
    const ushort* pB = lds + 16384;
#pragma unroll
    for (int nj = 0; nj < 4; ++nj) {
      bF[nj][0] = *(const bf16x8*)(pB + bbase + nj * 1024 + au0);
      bF[nj][1] = *(const bf16x8*)(pB + bbase + nj * 1024 + au1);
    }
  }

#define RDA(P)                                                      \
  aF[0][0] = *(const bf16x8*)(bAv + abase + (2 * (P)) * 2048 + au0); \
  aF[0][1] = *(const bf16x8*)(bAv + abase + (2 * (P)) * 2048 + au1); \
  aF[1][0] = *(const bf16x8*)(bAv + abase + (2 * (P) + 1) * 2048 + au0); \
  aF[1][1] = *(const bf16x8*)(bAv + abase + (2 * (P) + 1) * 2048 + au1);

#define MFMA16(P)                                                   \
  __builtin_amdgcn_s_setprio(1);                                    \
  _Pragma("unroll")                                                 \
  for (int kk = 0; kk < 2; ++kk) {                                  \
    _Pragma("unroll")                                               \
    for (int mi2 = 0; mi2 < 2; ++mi2) {                             \
      _Pragma("unroll")                                             \
      for (int nj = 0; nj < 4; ++nj)                                \
        acc[2 * (P) + mi2][nj] = __builtin_amdgcn_mfma_f32_16x16x32_bf16( \
            aF[mi2][kk], bF[nj][kk], acc[2 * (P) + mi2][nj], 0, 0, 0); \
    }                                                               \
  }                                                                 \
  __builtin_amdgcn_s_setprio(0);

  const int T = K >> 6;
#pragma unroll 1
  for (int t = 0; t < T; ++t) {
    const int b = t & 1;
    ushort* bAv = lds + b * 32768;
    ushort* nAv = lds + (b ^ 1) * 32768;
    ushort* nBv = nAv + 16384;
    const bool pre = (t + 1 < T);

    // phase 0: read A-quarter 0 (B frags already in regs); stage Bq0,Bq1
    RDA(0);
    if (pre) { stq(sB, qstep, 0, nBv, tid); stq(sB, qstep, 1, nBv, tid);
               asm volatile("s_waitcnt vmcnt(4)" ::: "memory"); }
    else     { asm volatile("s_waitcnt vmcnt(2)" ::: "memory"); }
    __builtin_amdgcn_s_barrier();
    MFMA16(0);
    __builtin_amdgcn_s_barrier();

    // phase 1: A-quarter 1; stage Bq2,Bq3
    RDA(1);
    if (pre) { stq(sB, qstep, 2, nBv, tid); stq(sB, qstep, 3, nBv, tid);
               asm volatile("s_waitcnt vmcnt(5)" ::: "memory"); }
    else     { asm volatile("s_waitcnt vmcnt(1)" ::: "memory"); }
    __builtin_amdgcn_s_barrier();
    MFMA16(1);
    __builtin_amdgcn_s_barrier();

    // phase 2: A-quarter 2; stage Aq0,Aq1
    RDA(2);
    if (pre) { stq(sA, qstep, 0, nAv, tid); stq(sA, qstep, 1, nAv, tid);
               asm volatile("s_waitcnt vmcnt(6)" ::: "memory"); }
    else     { asm volatile("s_waitcnt vmcnt(0)" ::: "memory"); }
    __builtin_amdgcn_s_barrier();
    MFMA16(2);
    __builtin_amdgcn_s_barrier();

    // phase 3: A-quarter 3; stage Aq2,Aq3; after MFMA(3), prefetch next-tile
    // B fragments from nBv into bF (landed per vmcnt(3)).
    RDA(3);
    if (pre) { stq(sA, qstep, 2, nAv, tid); stq(sA, qstep, 3, nAv, tid);
               asm volatile("s_waitcnt vmcnt(3)" ::: "memory"); }
    __builtin_amdgcn_s_barrier();
    MFMA16(3);
    if (pre) {
#pragma unroll
      for (int nj = 0; nj < 4; ++nj) {
        bF[nj][0] = *(const bf16x8*)(nBv + bbase + nj * 1024 + au0);
        bF[nj][1] = *(const bf16x8*)(nBv + bbase + nj * 1024 + au1);
      }
    }
    __builtin_amdgcn_s_barrier();

    if (pre) { sA += 64; sB += 64; }
  }
#undef RDA
#undef MFMA16

  // epilogue: C/D map col=lane&15, row=(lane>>4)*4+e (m89)
#pragma unroll
  for (int mi = 0; mi < 8; ++mi)
#pragma unroll
    for (int nj = 0; nj < 4; ++nj)
#pragma unroll
      for (int e = 0; e < 4; ++e) {
        int row = m0 + wr * 16 + mi * 32 + fq * 4 + e;
        int col = colbase + n0 + wc * 64 + nj * 16 + fr;
        float v = acc[mi][nj][e];
        if (F32OUT) {
          Cf[(size_t)row * ldc + col] = v;
        } else {
          v = v > 0.0f ? v : 0.0f;
          Ch[(size_t)row * ldc + col] = f2bf(v);
        }
      }
}

// run one layer: merged mat (all slices, one launch) + gemm256 per N-chunk
template <int A, int B, int CC, int M, int K, bool F32OUT>
static void run_layer256(const ushort* Ain, const float* tbl, ushort* hOut, float* fOut,
                         int N, int ldc, ushort* wb, size_t avail, hipStream_t stream) {
  constexpr int S = 1 << 19;  // 2MB f32 slice
  constexpr int NSL = M / S;
  long ncmax = (long)(avail / (size_t)((size_t)K * 2));
  ncmax = (ncmax / 256) * 256;
  if (ncmax > N) ncmax = N;
  if (ncmax < 256) ncmax = 256;
  for (int n0 = 0; n0 < N; n0 += (int)ncmax) {
    int nc = (N - n0 < (int)ncmax) ? (N - n0) : (int)ncmax;
    int bps = (nc + 3) / 4;
    hipLaunchKernelGGL((mat_all_kernel<A, B, CC, M, K, S>),
                       dim3((unsigned)(bps * NSL)), dim3(256), 0, stream,
                       tbl, wb, n0, nc, bps);
    dim3 g((unsigned)((nc / 256) * 8));
    hipLaunchKernelGGL((gemm256<F32OUT>), g, dim3(512), 0, stream,
                       Ain, wb, fOut, hOut, K, ldc, n0, 8);
  }
}

extern "C" void kernel_launch(void* const* d_in, const int* in_sizes, int n_in,
                              void* d_out, int out_size, void* d_ws, size_t ws_size,
                              hipStream_t stream) {
  const float* x   = (const float*)d_in[0];
  const float* hw0 = (const float*)d_in[1];
  const float* hw1 = (const float*)d_in[2];
  const float* hw2 = (const float*)d_in[3];
  float* out = (float*)d_out;
  uint8_t* ws = (uint8_t*)d_ws;

  ushort* xb = (ushort*)(ws + 0);                     // 2048x1024 bf16  (4 MB)
  ushort* h1 = (ushort*)(ws + ((size_t)4 << 20));     // 2048x4096 bf16 (16 MB)
  ushort* h2 = (ushort*)(ws + ((size_t)20 << 20));    // 2048x4096 bf16 (16 MB)
  ushort* wb = (ushort*)(ws + ((size_t)36 << 20));    // W^T chunk buffer
  size_t avail = ws_size > ((size_t)36 << 20) ? ws_size - ((size_t)36 << 20)
                                              : (size_t)(128 * 4096 * 2);

  hipLaunchKernelGGL(cvt_bf16_kernel, dim3(1024), dim3(256), 0, stream,
                     (const float4*)x, (ushort4*)xb, 2048 * 1024 / 4);

  // layer 0: [2048,1024] @ [1024,4096], relu -> h1 (bf16)
  run_layer256<9973, 31013, 557, 1 << 20, 1024, false>(
      xb, hw0, h1, nullptr, 4096, 4096, wb, avail, stream);
  // layer 1: [2048,4096] @ [4096,4096], relu -> h2 (bf16)
  run_layer256<10007, 31019, 563, 1 << 20, 4096, false>(
      h1, hw1, h2, nullptr, 4096, 4096, wb, avail, stream);
  // layer 2: [2048,4096] @ [4096,32000] -> out (f32)
  run_layer256<10039, 31039, 569, 1 << 22, 4096, true>(
      h2, hw2, nullptr, out, 32000, 32000, wb, avail, stream);
}

// Round 7
// 934.675 us; speedup vs baseline: 1.3226x; 1.2913x over previous
//
#include <hip/hip_runtime.h>
#include <stdint.h>

typedef __attribute__((ext_vector_type(8))) short bf16x8;
typedef __attribute__((ext_vector_type(4))) float f32x4;

__device__ __forceinline__ ushort f2bf(float f) {
  union { float f; uint32_t u; } v; v.f = f;
  return (ushort)((v.u + 0x7FFFu + ((v.u >> 16) & 1u)) >> 16);
}

__device__ __forceinline__ void load_lds16(const void* g, void* l) {
  __builtin_amdgcn_global_load_lds(
      (const __attribute__((address_space(1))) void*)g,
      (__attribute__((address_space(3))) void*)l, 16, 0, 0);
}

// ---- convert x (f32) -> bf16 ----
__global__ void cvt_bf16_kernel(const float4* __restrict__ x, ushort4* __restrict__ o, int n4) {
  int i = blockIdx.x * blockDim.x + threadIdx.x;
  int stride = gridDim.x * blockDim.x;
  for (; i < n4; i += stride) {
    float4 v = x[i];
    o[i] = make_ushort4(f2bf(v.x), f2bf(v.y), f2bf(v.z), f2bf(v.w));
  }
}

// ---- LDS-staged W^T materialization ----
// Subslice of SL=2^15 f32 (128 KB) staged in LDS (coalesced). Gathers hit LDS
// (bank stride A mod 32 = odd -> near-conflict-free) instead of 53 distinct L2
// lines per wave. Wrap loop flattened across the wave: lane -> (j=lane>>2,
// pos=lane&3); run length <= ceil(SL/A) = 4.
template <int A, int B, int CC, int M, int K, int SL>
__global__ __launch_bounds__(512) void mat_lds_kernel(
    const float* __restrict__ t, ushort* __restrict__ wt, int n0, int nc, int bps) {
  const int sub = blockIdx.x / bps;
  const int blk = blockIdx.x - sub * bps;
  const int lo = sub * SL;
  __shared__ float sl[SL];
  // stage subslice: 512 threads x 16B, 16 iters, linear dest
  {
    const float* src = t + lo;
    const int tid = threadIdx.x;
#pragma unroll
    for (int it4 = 0; it4 < SL / 4; it4 += 512) {
      load_lds16(src + (size_t)(it4 + tid) * 4, (char*)sl + (size_t)(it4 + tid) * 16);
    }
  }
  asm volatile("s_waitcnt vmcnt(0)" ::: "memory");
  __syncthreads();

  const int w = threadIdx.x >> 6, lane = threadIdx.x & 63;
  const int jq = lane >> 2, pos = lane & 3;
  constexpr int J = (int)(((long)(K - 1) * A + (M - 1)) / M) + 1;  // max wraps
  constexpr int BIAS = 1024;  // A*BIAS > M for all layers
  const int rpb = (nc + bps - 1) / bps;
  const int rlo = blk * rpb;
  const int rhi = (nc < rlo + rpb) ? nc : (rlo + rpb);

#pragma unroll 2
  for (int r = rlo + w; r < rhi; r += 8) {
    const int n = n0 + r;
    const int offs = (int)(((unsigned)((long)n * B + CC)) & (unsigned)(M - 1));
    ushort* wrow = wt + (size_t)r * K;
#pragma unroll
    for (int jb = 0; jb < J; jb += 16) {
      const int jj = jb + jq;
      const int D = jj * M + lo - offs;
      const int kL = (int)((unsigned)(D + A * BIAS + A - 1) / (unsigned)A) - BIAS;
      const int kU = (int)((unsigned)(D + SL + A * BIAS + A - 1) / (unsigned)A) - BIAS;
      const int k = kL + pos;
      if (k < kU && k < K && k >= 0) {
        const int idx = k * A - D;  // in [0, SL)
        wrow[k] = f2bf(sl[idx]);
      }
    }
  }
}

// ==== 256x256 8-wave 4-phase counted-vmcnt GEMM (unchanged from R5) ====
__device__ __forceinline__ void stq(const ushort* src, size_t qstep, int q,
                                    ushort* dstbase, int tid) {
  load_lds16(src + (size_t)q * qstep, dstbase + q * 4096 + tid * 8);
}

template <bool F32OUT>
__global__ __launch_bounds__(512, 2) void gemm256(
    const ushort* __restrict__ Ag, const ushort* __restrict__ Bg,
    float* __restrict__ Cf, ushort* __restrict__ Ch,
    int K, int ldc, int colbase, int mtiles) {
  __shared__ alignas(16) ushort lds[2 * 2 * 16384];  // 128 KiB
  const int tid = threadIdx.x;
  const int lane = tid & 63, w = tid >> 6;
  const int wr = w >> 2, wc = w & 3;
  const int fr = lane & 15, fq = lane >> 4, l7 = lane & 7;

  // bijective XCD swizzle (m204)
  const int nwg = (int)gridDim.x, bid = (int)blockIdx.x;
  const int q8 = nwg >> 3, r8 = nwg & 7;
  const int xcd = bid & 7, ix = bid >> 3;
  const int swz = (xcd < r8 ? xcd * (q8 + 1) : r8 * (q8 + 1) + (xcd - r8) * q8) + ix;
  const int m0 = (swz % mtiles) * 256;
  const int n0 = (swz / mtiles) * 256;

  const int rowq = tid >> 3;
  const int cswz = ((tid & 7) ^ (rowq & 7)) * 8;
  const ushort* sA = Ag + (size_t)(m0 + rowq) * K + cswz;
  const ushort* sB = Bg + (size_t)(n0 + rowq) * K + cswz;
  const size_t qstep = (size_t)64 * (size_t)K;

  const int au0 = ((0 * 4 + fq) ^ l7) * 8;
  const int au1 = ((1 * 4 + fq) ^ l7) * 8;
  const int abase = (wr * 16 + fr) * 64;
  const int bbase = (wc * 64 + fr) * 64;

  f32x4 acc[8][4] = {};
  bf16x8 aF[2][2], bF[4][2];

  // prologue: stage tile 0 into buf 0 (FIFO: B0..B3, A0..A3)
  {
    ushort* nAv = lds;
    ushort* nBv = lds + 16384;
    stq(sB, qstep, 0, nBv, tid); stq(sB, qstep, 1, nBv, tid);
    stq(sB, qstep, 2, nBv, tid); stq(sB, qstep, 3, nBv, tid);
    stq(sA, qstep, 0, nAv, tid); stq(sA, qstep, 1, nAv, tid);
    stq(sA, qstep, 2, nAv, tid); stq(sA, qstep, 3, nAv, tid);
    sA += 64; sB += 64;
  }
  asm volatile("s_waitcnt vmcnt(3)" ::: "memory");
  __builtin_amdgcn_s_barrier();
  // preload B fragments for tile 0
  {
    const ushort* pB = lds + 16384;
#pragma unroll
    for (int nj = 0; nj < 4; ++nj) {
      bF[nj][0] = *(const bf16x8*)(pB + bbase + nj * 1024 + au0);
      bF[nj][1] = *(const bf16x8*)(pB + bbase + nj * 1024 + au1);
    }
  }

#define RDA(P)                                                      \
  aF[0][0] = *(const bf16x8*)(bAv + abase + (2 * (P)) * 2048 + au0); \
  aF[0][1] = *(const bf16x8*)(bAv + abase + (2 * (P)) * 2048 + au1); \
  aF[1][0] = *(const bf16x8*)(bAv + abase + (2 * (P) + 1) * 2048 + au0); \
  aF[1][1] = *(const bf16x8*)(bAv + abase + (2 * (P) + 1) * 2048 + au1);

#define MFMA16(P)                                                   \
  __builtin_amdgcn_s_setprio(1);                                    \
  _Pragma("unroll")                                                 \
  for (int kk = 0; kk < 2; ++kk) {                                  \
    _Pragma("unroll")                                               \
    for (int mi2 = 0; mi2 < 2; ++mi2) {                             \
      _Pragma("unroll")                                             \
      for (int nj = 0; nj < 4; ++nj)                                \
        acc[2 * (P) + mi2][nj] = __builtin_amdgcn_mfma_f32_16x16x32_bf16( \
            aF[mi2][kk], bF[nj][kk], acc[2 * (P) + mi2][nj], 0, 0, 0); \
    }                                                               \
  }                                                                 \
  __builtin_amdgcn_s_setprio(0);

  const int T = K >> 6;
#pragma unroll 1
  for (int t = 0; t < T; ++t) {
    const int b = t & 1;
    ushort* bAv = lds + b * 32768;
    ushort* nAv = lds + (b ^ 1) * 32768;
    ushort* nBv = nAv + 16384;
    const bool pre = (t + 1 < T);

    // phase 0
    RDA(0);
    if (pre) { stq(sB, qstep, 0, nBv, tid); stq(sB, qstep, 1, nBv, tid);
               asm volatile("s_waitcnt vmcnt(4)" ::: "memory"); }
    else     { asm volatile("s_waitcnt vmcnt(2)" ::: "memory"); }
    __builtin_amdgcn_s_barrier();
    MFMA16(0);
    __builtin_amdgcn_s_barrier();

    // phase 1
    RDA(1);
    if (pre) { stq(sB, qstep, 2, nBv, tid); stq(sB, qstep, 3, nBv, tid);
               asm volatile("s_waitcnt vmcnt(5)" ::: "memory"); }
    else     { asm volatile("s_waitcnt vmcnt(1)" ::: "memory"); }
    __builtin_amdgcn_s_barrier();
    MFMA16(1);
    __builtin_amdgcn_s_barrier();

    // phase 2
    RDA(2);
    if (pre) { stq(sA, qstep, 0, nAv, tid); stq(sA, qstep, 1, nAv, tid);
               asm volatile("s_waitcnt vmcnt(6)" ::: "memory"); }
    else     { asm volatile("s_waitcnt vmcnt(0)" ::: "memory"); }
    __builtin_amdgcn_s_barrier();
    MFMA16(2);
    __builtin_amdgcn_s_barrier();

    // phase 3 (+ next-tile B fragment prefetch after MFMA)
    RDA(3);
    if (pre) { stq(sA, qstep, 2, nAv, tid); stq(sA, qstep, 3, nAv, tid);
               asm volatile("s_waitcnt vmcnt(3)" ::: "memory"); }
    __builtin_amdgcn_s_barrier();
    MFMA16(3);
    if (pre) {
#pragma unroll
      for (int nj = 0; nj < 4; ++nj) {
        bF[nj][0] = *(const bf16x8*)(nBv + bbase + nj * 1024 + au0);
        bF[nj][1] = *(const bf16x8*)(nBv + bbase + nj * 1024 + au1);
      }
    }
    __builtin_amdgcn_s_barrier();

    if (pre) { sA += 64; sB += 64; }
  }
#undef RDA
#undef MFMA16

  // epilogue: C/D map col=lane&15, row=(lane>>4)*4+e (m89)
#pragma unroll
  for (int mi = 0; mi < 8; ++mi)
#pragma unroll
    for (int nj = 0; nj < 4; ++nj)
#pragma unroll
      for (int e = 0; e < 4; ++e) {
        int row = m0 + wr * 16 + mi * 32 + fq * 4 + e;
        int col = colbase + n0 + wc * 64 + nj * 16 + fr;
        float v = acc[mi][nj][e];
        if (F32OUT) {
          Cf[(size_t)row * ldc + col] = v;
        } else {
          v = v > 0.0f ? v : 0.0f;
          Ch[(size_t)row * ldc + col] = f2bf(v);
        }
      }
}

// run one layer: LDS-staged mat (one launch) + gemm256 per N-chunk
template <int A, int B, int CC, int M, int K, bool F32OUT>
static void run_layer256(const ushort* Ain, const float* tbl, ushort* hOut, float* fOut,
                         int N, int ldc, ushort* wb, size_t avail, hipStream_t stream) {
  constexpr int SL = 1 << 15;  // 128 KB f32 subslice (LDS-resident)
  constexpr int NSUB = M / SL;
  const int bps = (NSUB >= 256) ? 1 : (256 / NSUB);
  long ncmax = (long)(avail / (size_t)((size_t)K * 2));
  ncmax = (ncmax / 256) * 256;
  if (ncmax > N) ncmax = N;
  if (ncmax < 256) ncmax = 256;
  for (int n0 = 0; n0 < N; n0 += (int)ncmax) {
    int nc = (N - n0 < (int)ncmax) ? (N - n0) : (int)ncmax;
    hipLaunchKernelGGL((mat_lds_kernel<A, B, CC, M, K, SL>),
                       dim3((unsigned)(NSUB * bps)), dim3(512), 0, stream,
                       tbl, wb, n0, nc, bps);
    dim3 g((unsigned)((nc / 256) * 8));
    hipLaunchKernelGGL((gemm256<F32OUT>), g, dim3(512), 0, stream,
                       Ain, wb, fOut, hOut, K, ldc, n0, 8);
  }
}

extern "C" void kernel_launch(void* const* d_in, const int* in_sizes, int n_in,
                              void* d_out, int out_size, void* d_ws, size_t ws_size,
                              hipStream_t stream) {
  const float* x   = (const float*)d_in[0];
  const float* hw0 = (const float*)d_in[1];
  const float* hw1 = (const float*)d_in[2];
  const float* hw2 = (const float*)d_in[3];
  float* out = (float*)d_out;
  uint8_t* ws = (uint8_t*)d_ws;

  ushort* xb = (ushort*)(ws + 0);                     // 2048x1024 bf16  (4 MB)
  ushort* h1 = (ushort*)(ws + ((size_t)4 << 20));     // 2048x4096 bf16 (16 MB)
  ushort* h2 = (ushort*)(ws + ((size_t)20 << 20));    // 2048x4096 bf16 (16 MB)
  ushort* wb = (ushort*)(ws + ((size_t)36 << 20));    // W^T chunk buffer
  size_t avail = ws_size > ((size_t)36 << 20) ? ws_size - ((size_t)36 << 20)
                                              : (size_t)(128 * 4096 * 2);

  hipLaunchKernelGGL(cvt_bf16_kernel, dim3(1024), dim3(256), 0, stream,
                     (const float4*)x, (ushort4*)xb, 2048 * 1024 / 4);

  // layer 0: [2048,1024] @ [1024,4096], relu -> h1 (bf16)
  run_layer256<9973, 31013, 557, 1 << 20, 1024, false>(
      xb, hw0, h1, nullptr, 4096, 4096, wb, avail, stream);
  // layer 1: [2048,4096] @ [4096,4096], relu -> h2 (bf16)
  run_layer256<10007, 31019, 563, 1 << 20, 4096, false>(
      h1, hw1, h2, nullptr, 4096, 4096, wb, avail, stream);
  // layer 2: [2048,4096] @ [4096,32000] -> out (f32)
  run_layer256<10039, 31039, 569, 1 << 22, 4096, true>(
      h2, hw2, nullptr, out, 32000, 32000, wb, avail, stream);
}

// Round 9
// 897.447 us; speedup vs baseline: 1.3774x; 1.0415x over previous
//
#include <hip/hip_runtime.h>
#include <stdint.h>

typedef __attribute__((ext_vector_type(8))) short bf16x8;
typedef __attribute__((ext_vector_type(4))) float f32x4;

__device__ __forceinline__ ushort f2bf(float f) {
  union { float f; uint32_t u; } v; v.f = f;
  return (ushort)((v.u + 0x7FFFu + ((v.u >> 16) & 1u)) >> 16);
}

__device__ __forceinline__ void load_lds16(const void* g, void* l) {
  __builtin_amdgcn_global_load_lds(
      (const __attribute__((address_space(1))) void*)g,
      (__attribute__((address_space(3))) void*)l, 16, 0, 0);
}

template <int N>
__device__ __forceinline__ void waitvm() {
  asm volatile("s_waitcnt vmcnt(%0)" :: "n"(N) : "memory");
}

// ---- convert x (f32) -> bf16 ----
__global__ void cvt_bf16_kernel(const float4* __restrict__ x, ushort4* __restrict__ o, int n4) {
  int i = blockIdx.x * blockDim.x + threadIdx.x;
  int stride = gridDim.x * blockDim.x;
  for (; i < n4; i += stride) {
    float4 v = x[i];
    o[i] = make_ushort4(f2bf(v.x), f2bf(v.y), f2bf(v.z), f2bf(v.w));
  }
}

// ---- LDS-staged W^T materialization (unchanged from R6) ----
template <int A, int B, int CC, int M, int K, int SL>
__global__ __launch_bounds__(512) void mat_lds_kernel(
    const float* __restrict__ t, ushort* __restrict__ wt, int n0, int nc, int bps) {
  const int sub = blockIdx.x / bps;
  const int blk = blockIdx.x - sub * bps;
  const int lo = sub * SL;
  __shared__ float sl[SL];
  {
    const float* src = t + lo;
    const int tid = threadIdx.x;
#pragma unroll
    for (int it4 = 0; it4 < SL / 4; it4 += 512) {
      load_lds16(src + (size_t)(it4 + tid) * 4, (char*)sl + (size_t)(it4 + tid) * 16);
    }
  }
  asm volatile("s_waitcnt vmcnt(0)" ::: "memory");
  __syncthreads();

  const int w = threadIdx.x >> 6, lane = threadIdx.x & 63;
  const int jq = lane >> 2, pos = lane & 3;
  constexpr int J = (int)(((long)(K - 1) * A + (M - 1)) / M) + 1;
  constexpr int BIAS = 1024;
  const int rpb = (nc + bps - 1) / bps;
  const int rlo = blk * rpb;
  const int rhi = (nc < rlo + rpb) ? nc : (rlo + rpb);

#pragma unroll 2
  for (int r = rlo + w; r < rhi; r += 8) {
    const int n = n0 + r;
    const int offs = (int)(((unsigned)((long)n * B + CC)) & (unsigned)(M - 1));
    ushort* wrow = wt + (size_t)r * K;
#pragma unroll
    for (int jb = 0; jb < J; jb += 16) {
      const int jj = jb + jq;
      const int D = jj * M + lo - offs;
      const int kL = (int)((unsigned)(D + A * BIAS + A - 1) / (unsigned)A) - BIAS;
      const int kU = (int)((unsigned)(D + SL + A * BIAS + A - 1) / (unsigned)A) - BIAS;
      const int k = kL + pos;
      if (k < kU && k < K && k >= 0) {
        const int idx = k * A - D;  // in [0, SL)
        wrow[k] = f2bf(sl[idx]);
      }
    }
  }
}

// ==== BMx256 8-wave 4-phase counted-vmcnt GEMM ====
// CONSTRAINT (R7 lesson): a vmcnt wait protects a staged LDS quarter only if
// it precedes, in program order, the ds_read that samples it — the ds_read
// races the global_load_lds write otherwise. So quarter read at phase P must
// be retired by the wait at phase P-1 (or earlier).
// BM=256 FIFO {B0,B1|B2,B3|A0,A1|A2,A3}: minimal waits {4,5,6,3}, last {2,1,0,-}.
// BM=128 FIFO {B0,B1|B2,B3|A0|A1}, A0 read at ph0/1, A1 at ph2/3:
//   waits {-,4,-,1}, last {-,0,-,-}.
__device__ __forceinline__ void stq(const ushort* src, size_t qstep, int q,
                                    ushort* dstbase, int tid) {
  load_lds16(src + (size_t)q * qstep, dstbase + q * 4096 + tid * 8);
}

template <int BM, bool F32OUT>
__global__ __launch_bounds__(512, 2) void gemm256(
    const ushort* __restrict__ Ag, const ushort* __restrict__ Bg,
    float* __restrict__ Cf, ushort* __restrict__ Ch,
    int K, int ldc, int colbase, int mtiles) {
  constexpr int NA = BM / 64;          // A stq's per tile (4 or 2)
  constexpr int MS = BM / 128;         // m-subtiles per phase (2 or 1)
  constexpr int MR = BM / 32;          // acc rows
  constexpr int AE = BM * 64;          // A ushorts per buffer
  constexpr int BE = 256 * 64;
  constexpr int BUF = AE + BE;
  __shared__ alignas(16) ushort lds[2 * BUF];
  const int tid = threadIdx.x;
  const int lane = tid & 63, w = tid >> 6;
  const int wr = w >> 2, wc = w & 3;
  const int fr = lane & 15, fq = lane >> 4, l7 = lane & 7;

  // bijective XCD swizzle (m204)
  const int nwg = (int)gridDim.x, bid = (int)blockIdx.x;
  const int q8 = nwg >> 3, r8 = nwg & 7;
  const int xcd = bid & 7, ix = bid >> 3;
  const int swz = (xcd < r8 ? xcd * (q8 + 1) : r8 * (q8 + 1) + (xcd - r8) * q8) + ix;
  const int m0 = (swz % mtiles) * BM;
  const int n0 = (swz / mtiles) * 256;

  const int rowq = tid >> 3;
  const int cswz = ((tid & 7) ^ (rowq & 7)) * 8;
  const ushort* sA = Ag + (size_t)(m0 + rowq) * K + cswz;
  const ushort* sB = Bg + (size_t)(n0 + rowq) * K + cswz;
  const size_t qstep = (size_t)64 * (size_t)K;

  const int au0 = ((0 * 4 + fq) ^ l7) * 8;
  const int au1 = ((1 * 4 + fq) ^ l7) * 8;
  const int abase = (wr * 16 + fr) * 64;
  const int bbase = (wc * 64 + fr) * 64;

  f32x4 acc[MR][4] = {};
  bf16x8 aF[2][2], bF[4][2];

  // prologue: stage tile 0 into buf 0 (FIFO: B0..B3, A0..A_{NA-1})
  {
    ushort* nAv = lds;
    ushort* nBv = lds + AE;
    stq(sB, qstep, 0, nBv, tid); stq(sB, qstep, 1, nBv, tid);
    stq(sB, qstep, 2, nBv, tid); stq(sB, qstep, 3, nBv, tid);
#pragma unroll
    for (int q = 0; q < NA; ++q) stq(sA, qstep, q, nAv, tid);
    sA += 64; sB += 64;
  }
  waitvm<NA - 1>();   // retires B0..B3 and A0 (leaves A1.. / A1..A3)
  __builtin_amdgcn_s_barrier();
  // preload B fragments for tile 0 (B all landed)
  {
    const ushort* pB = lds + AE;
#pragma unroll
    for (int nj = 0; nj < 4; ++nj) {
      bF[nj][0] = *(const bf16x8*)(pB + bbase + nj * 1024 + au0);
      bF[nj][1] = *(const bf16x8*)(pB + bbase + nj * 1024 + au1);
    }
  }

#define RDSUB(P)                                                        \
  _Pragma("unroll")                                                     \
  for (int mi2 = 0; mi2 < MS; ++mi2) {                                  \
    aF[mi2][0] = *(const bf16x8*)(bAv + abase + ((P) * MS + mi2) * 2048 + au0); \
    aF[mi2][1] = *(const bf16x8*)(bAv + abase + ((P) * MS + mi2) * 2048 + au1); \
  }

#define MFMAPH(P)                                                       \
  __builtin_amdgcn_s_setprio(1);                                        \
  _Pragma("unroll")                                                     \
  for (int kk = 0; kk < 2; ++kk) {                                      \
    _Pragma("unroll")                                                   \
    for (int mi2 = 0; mi2 < MS; ++mi2) {                                \
      _Pragma("unroll")                                                 \
      for (int nj = 0; nj < 4; ++nj)                                    \
        acc[(P) * MS + mi2][nj] = __builtin_amdgcn_mfma_f32_16x16x32_bf16( \
            aF[mi2][kk], bF[nj][kk], acc[(P) * MS + mi2][nj], 0, 0, 0); \
    }                                                                   \
  }                                                                     \
  __builtin_amdgcn_s_setprio(0);

  const int T = K >> 6;
#pragma unroll 1
  for (int t = 0; t < T; ++t) {
    const int b = t & 1;
    ushort* bAv = lds + b * BUF;
    ushort* nAv = lds + (b ^ 1) * BUF;
    ushort* nBv = nAv + AE;
    const bool pre = (t + 1 < T);

    // phase 0: stage Bq0,Bq1
    RDSUB(0);
    if (pre) { stq(sB, qstep, 0, nBv, tid); stq(sB, qstep, 1, nBv, tid);
               if (BM == 256) waitvm<4>(); }
    else     { if (BM == 256) waitvm<2>(); }
    __builtin_amdgcn_s_barrier();
    MFMAPH(0);
    __builtin_amdgcn_s_barrier();

    // phase 1: stage Bq2,Bq3
    RDSUB(1);
    if (pre) { stq(sB, qstep, 2, nBv, tid); stq(sB, qstep, 3, nBv, tid);
               waitvm<(BM == 256) ? 5 : 4>(); }
    else     { waitvm<(BM == 256) ? 1 : 0>(); }
    __builtin_amdgcn_s_barrier();
    MFMAPH(1);
    __builtin_amdgcn_s_barrier();

    // phase 2: stage A first half
    RDSUB(2);
    if (pre) {
#pragma unroll
      for (int q = 0; q < NA / 2; ++q) stq(sA, qstep, q, nAv, tid);
      if (BM == 256) waitvm<6>();
    } else { if (BM == 256) waitvm<0>(); }
    __builtin_amdgcn_s_barrier();
    MFMAPH(2);
    __builtin_amdgcn_s_barrier();

    // phase 3: stage A second half; after MFMA, prefetch next-tile B frags
    RDSUB(3);
    if (pre) {
#pragma unroll
      for (int q = NA / 2; q < NA; ++q) stq(sA, qstep, q, nAv, tid);
      waitvm<(BM == 256) ? 3 : 1>();   // retires B0'..B3' and A0'
    }
    __builtin_amdgcn_s_barrier();
    MFMAPH(3);
    if (pre) {
#pragma unroll
      for (int nj = 0; nj < 4; ++nj) {
        bF[nj][0] = *(const bf16x8*)(nBv + bbase + nj * 1024 + au0);
        bF[nj][1] = *(const bf16x8*)(nBv + bbase + nj * 1024 + au1);
      }
    }
    __builtin_amdgcn_s_barrier();

    if (pre) { sA += 64; sB += 64; }
  }
#undef RDSUB
#undef MFMAPH

  // epilogue: C/D map col=lane&15, row=(lane>>4)*4+e (m89)
#pragma unroll
  for (int mi = 0; mi < MR; ++mi)
#pragma unroll
    for (int nj = 0; nj < 4; ++nj)
#pragma unroll
      for (int e = 0; e < 4; ++e) {
        int row = m0 + wr * 16 + mi * 32 + fq * 4 + e;
        int col = colbase + n0 + wc * 64 + nj * 16 + fr;
        float v = acc[mi][nj][e];
        if (F32OUT) {
          Cf[(size_t)row * ldc + col] = v;
        } else {
          v = v > 0.0f ? v : 0.0f;
          Ch[(size_t)row * ldc + col] = f2bf(v);
        }
      }
}

// run one layer: LDS-staged mat (one launch) + gemm per N-chunk
template <int A, int B, int CC, int M, int K, int BM, bool F32OUT>
static void run_layer256(const ushort* Ain, const float* tbl, ushort* hOut, float* fOut,
                         int N, int ldc, ushort* wb, size_t avail, hipStream_t stream) {
  constexpr int SL = 1 << 15;  // 128 KB f32 subslice (LDS-resident)
  constexpr int NSUB = M / SL;
  const int bps = (NSUB >= 256) ? 1 : (256 / NSUB);
  long ncmax = (long)(avail / (size_t)((size_t)K * 2));
  ncmax = (ncmax / 256) * 256;
  if (ncmax > N) ncmax = N;
  if (ncmax < 256) ncmax = 256;
  const int mtiles = 2048 / BM;
  for (int n0 = 0; n0 < N; n0 += (int)ncmax) {
    int nc = (N - n0 < (int)ncmax) ? (N - n0) : (int)ncmax;
    hipLaunchKernelGGL((mat_lds_kernel<A, B, CC, M, K, SL>),
                       dim3((unsigned)(NSUB * bps)), dim3(512), 0, stream,
                       tbl, wb, n0, nc, bps);
    dim3 g((unsigned)((nc / 256) * mtiles));
    hipLaunchKernelGGL((gemm256<BM, F32OUT>), g, dim3(512), 0, stream,
                       Ain, wb, fOut, hOut, K, ldc, n0, mtiles);
  }
}

extern "C" void kernel_launch(void* const* d_in, const int* in_sizes, int n_in,
                              void* d_out, int out_size, void* d_ws, size_t ws_size,
                              hipStream_t stream) {
  const float* x   = (const float*)d_in[0];
  const float* hw0 = (const float*)d_in[1];
  const float* hw1 = (const float*)d_in[2];
  const float* hw2 = (const float*)d_in[3];
  float* out = (float*)d_out;
  uint8_t* ws = (uint8_t*)d_ws;

  ushort* xb = (ushort*)(ws + 0);                     // 2048x1024 bf16  (4 MB)
  ushort* h1 = (ushort*)(ws + ((size_t)4 << 20));     // 2048x4096 bf16 (16 MB)
  ushort* h2 = (ushort*)(ws + ((size_t)20 << 20));    // 2048x4096 bf16 (16 MB)
  ushort* wb = (ushort*)(ws + ((size_t)36 << 20));    // W^T chunk buffer
  size_t avail = ws_size > ((size_t)36 << 20) ? ws_size - ((size_t)36 << 20)
                                              : (size_t)(128 * 4096 * 2);

  hipLaunchKernelGGL(cvt_bf16_kernel, dim3(1024), dim3(256), 0, stream,
                     (const float4*)x, (ushort4*)xb, 2048 * 1024 / 4);

  // layer 0: [2048,1024] @ [1024,4096], relu -> h1 (bf16)  [BM=128, 256 blocks]
  run_layer256<9973, 31013, 557, 1 << 20, 1024, 128, false>(
      xb, hw0, h1, nullptr, 4096, 4096, wb, avail, stream);
  // layer 1: [2048,4096] @ [4096,4096], relu -> h2 (bf16)  [BM=128, 256 blocks]
  run_layer256<10007, 31019, 563, 1 << 20, 4096, 128, false>(
      h1, hw1, h2, nullptr, 4096, 4096, wb, avail, stream);
  // layer 2: [2048,4096] @ [4096,32000] -> out (f32)       [BM=256, 1000 blocks]
  run_layer256<10039, 31039, 569, 1 << 22, 4096, 256, true>(
      h2, hw2, nullptr, out, 32000, 32000, wb, avail, stream);
}

// Round 11
// 888.221 us; speedup vs baseline: 1.3917x; 1.0104x over previous
//
#include <hip/hip_runtime.h>
#include <stdint.h>

typedef __attribute__((ext_vector_type(8))) short bf16x8;
typedef __attribute__((ext_vector_type(4))) float f32x4;

__device__ __forceinline__ ushort f2bf(float f) {
  union { float f; uint32_t u; } v; v.f = f;
  return (ushort)((v.u + 0x7FFFu + ((v.u >> 16) & 1u)) >> 16);
}

__device__ __forceinline__ void load_lds16(const void* g, void* l) {
  __builtin_amdgcn_global_load_lds(
      (const __attribute__((address_space(1))) void*)g,
      (__attribute__((address_space(3))) void*)l, 16, 0, 0);
}

template <int N>
__device__ __forceinline__ void waitvm() {
  asm volatile("s_waitcnt vmcnt(%0)" :: "n"(N) : "memory");
}

// ---- convert x (f32) -> bf16 ----
__global__ void cvt_bf16_kernel(const float4* __restrict__ x, ushort4* __restrict__ o, int n4) {
  int i = blockIdx.x * blockDim.x + threadIdx.x;
  int stride = gridDim.x * blockDim.x;
  for (; i < n4; i += stride) {
    float4 v = x[i];
    o[i] = make_ushort4(f2bf(v.x), f2bf(v.y), f2bf(v.z), f2bf(v.w));
  }
}

// ---- LDS-staged W^T materialization (unchanged from R6) ----
template <int A, int B, int CC, int M, int K, int SL>
__global__ __launch_bounds__(512) void mat_lds_kernel(
    const float* __restrict__ t, ushort* __restrict__ wt, int n0, int nc, int bps) {
  const int sub = blockIdx.x / bps;
  const int blk = blockIdx.x - sub * bps;
  const int lo = sub * SL;
  __shared__ float sl[SL];
  {
    const float* src = t + lo;
    const int tid = threadIdx.x;
#pragma unroll
    for (int it4 = 0; it4 < SL / 4; it4 += 512) {
      load_lds16(src + (size_t)(it4 + tid) * 4, (char*)sl + (size_t)(it4 + tid) * 16);
    }
  }
  asm volatile("s_waitcnt vmcnt(0)" ::: "memory");
  __syncthreads();

  const int w = threadIdx.x >> 6, lane = threadIdx.x & 63;
  const int jq = lane >> 2, pos = lane & 3;
  constexpr int J = (int)(((long)(K - 1) * A + (M - 1)) / M) + 1;
  constexpr int BIAS = 1024;
  const int rpb = (nc + bps - 1) / bps;
  const int rlo = blk * rpb;
  const int rhi = (nc < rlo + rpb) ? nc : (rlo + rpb);

#pragma unroll 2
  for (int r = rlo + w; r < rhi; r += 8) {
    const int n = n0 + r;
    const int offs = (int)(((unsigned)((long)n * B + CC)) & (unsigned)(M - 1));
    ushort* wrow = wt + (size_t)r * K;
#pragma unroll
    for (int jb = 0; jb < J; jb += 16) {
      const int jj = jb + jq;
      const int D = jj * M + lo - offs;
      const int kL = (int)((unsigned)(D + A * BIAS + A - 1) / (unsigned)A) - BIAS;
      const int kU = (int)((unsigned)(D + SL + A * BIAS + A - 1) / (unsigned)A) - BIAS;
      const int k = kL + pos;
      if (k < kU && k < K && k >= 0) {
        const int idx = k * A - D;  // in [0, SL)
        wrow[k] = f2bf(sl[idx]);
      }
    }
  }
}

// ---- BM=128 4-phase GEMM (proven R8 schedule; layers 0/1) ----
__device__ __forceinline__ void stq(const ushort* src, size_t qstep, int q,
                                    ushort* dstbase, int tid) {
  load_lds16(src + (size_t)q * qstep, dstbase + q * 4096 + tid * 8);
}

template <int BM, bool F32OUT>
__global__ __launch_bounds__(512, 2) void gemm256(
    const ushort* __restrict__ Ag, const ushort* __restrict__ Bg,
    float* __restrict__ Cf, ushort* __restrict__ Ch,
    int K, int ldc, int colbase, int mtiles) {
  constexpr int NA = BM / 64;
  constexpr int MS = BM / 128;
  constexpr int MR = BM / 32;
  constexpr int AE = BM * 64;
  constexpr int BE = 256 * 64;
  constexpr int BUF = AE + BE;
  __shared__ alignas(16) ushort lds[2 * BUF];
  const int tid = threadIdx.x;
  const int lane = tid & 63, w = tid >> 6;
  const int wr = w >> 2, wc = w & 3;
  const int fr = lane & 15, fq = lane >> 4, l7 = lane & 7;

  const int nwg = (int)gridDim.x, bid = (int)blockIdx.x;
  const int q8 = nwg >> 3, r8 = nwg & 7;
  const int xcd = bid & 7, ix = bid >> 3;
  const int swz = (xcd < r8 ? xcd * (q8 + 1) : r8 * (q8 + 1) + (xcd - r8) * q8) + ix;
  const int m0 = (swz % mtiles) * BM;
  const int n0 = (swz / mtiles) * 256;

  const int rowq = tid >> 3;
  const int cswz = ((tid & 7) ^ (rowq & 7)) * 8;
  const ushort* sA = Ag + (size_t)(m0 + rowq) * K + cswz;
  const ushort* sB = Bg + (size_t)(n0 + rowq) * K + cswz;
  const size_t qstep = (size_t)64 * (size_t)K;

  const int au0 = ((0 * 4 + fq) ^ l7) * 8;
  const int au1 = ((1 * 4 + fq) ^ l7) * 8;
  const int abase = (wr * 16 + fr) * 64;
  const int bbase = (wc * 64 + fr) * 64;

  f32x4 acc[MR][4] = {};
  bf16x8 aF[2][2], bF[4][2];

  {
    ushort* nAv = lds;
    ushort* nBv = lds + AE;
    stq(sB, qstep, 0, nBv, tid); stq(sB, qstep, 1, nBv, tid);
    stq(sB, qstep, 2, nBv, tid); stq(sB, qstep, 3, nBv, tid);
#pragma unroll
    for (int q = 0; q < NA; ++q) stq(sA, qstep, q, nAv, tid);
    sA += 64; sB += 64;
  }
  waitvm<NA - 1>();
  __builtin_amdgcn_s_barrier();
  {
    const ushort* pB = lds + AE;
#pragma unroll
    for (int nj = 0; nj < 4; ++nj) {
      bF[nj][0] = *(const bf16x8*)(pB + bbase + nj * 1024 + au0);
      bF[nj][1] = *(const bf16x8*)(pB + bbase + nj * 1024 + au1);
    }
  }

#define RDSUB(P)                                                        \
  _Pragma("unroll")                                                     \
  for (int mi2 = 0; mi2 < MS; ++mi2) {                                  \
    aF[mi2][0] = *(const bf16x8*)(bAv + abase + ((P) * MS + mi2) * 2048 + au0); \
    aF[mi2][1] = *(const bf16x8*)(bAv + abase + ((P) * MS + mi2) * 2048 + au1); \
  }

#define MFMAPH(P)                                                       \
  __builtin_amdgcn_s_setprio(1);                                        \
  _Pragma("unroll")                                                     \
  for (int kk = 0; kk < 2; ++kk) {                                      \
    _Pragma("unroll")                                                   \
    for (int mi2 = 0; mi2 < MS; ++mi2) {                                \
      _Pragma("unroll")                                                 \
      for (int nj = 0; nj < 4; ++nj)                                    \
        acc[(P) * MS + mi2][nj] = __builtin_amdgcn_mfma_f32_16x16x32_bf16( \
            aF[mi2][kk], bF[nj][kk], acc[(P) * MS + mi2][nj], 0, 0, 0); \
    }                                                                   \
  }                                                                     \
  __builtin_amdgcn_s_setprio(0);

  const int T = K >> 6;
#pragma unroll 1
  for (int t = 0; t < T; ++t) {
    const int b = t & 1;
    ushort* bAv = lds + b * BUF;
    ushort* nAv = lds + (b ^ 1) * BUF;
    ushort* nBv = nAv + AE;
    const bool pre = (t + 1 < T);

    RDSUB(0);
    if (pre) { stq(sB, qstep, 0, nBv, tid); stq(sB, qstep, 1, nBv, tid);
               if (BM == 256) waitvm<4>(); }
    else     { if (BM == 256) waitvm<2>(); }
    __builtin_amdgcn_s_barrier();
    MFMAPH(0);
    __builtin_amdgcn_s_barrier();

    RDSUB(1);
    if (pre) { stq(sB, qstep, 2, nBv, tid); stq(sB, qstep, 3, nBv, tid);
               waitvm<(BM == 256) ? 5 : 4>(); }
    else     { waitvm<(BM == 256) ? 1 : 0>(); }
    __builtin_amdgcn_s_barrier();
    MFMAPH(1);
    __builtin_amdgcn_s_barrier();

    RDSUB(2);
    if (pre) {
#pragma unroll
      for (int q = 0; q < NA / 2; ++q) stq(sA, qstep, q, nAv, tid);
      if (BM == 256) waitvm<6>();
    } else { if (BM == 256) waitvm<0>(); }
    __builtin_amdgcn_s_barrier();
    MFMAPH(2);
    __builtin_amdgcn_s_barrier();

    RDSUB(3);
    if (pre) {
#pragma unroll
      for (int q = NA / 2; q < NA; ++q) stq(sA, qstep, q, nAv, tid);
      waitvm<(BM == 256) ? 3 : 1>();
    }
    __builtin_amdgcn_s_barrier();
    MFMAPH(3);
    if (pre) {
#pragma unroll
      for (int nj = 0; nj < 4; ++nj) {
        bF[nj][0] = *(const bf16x8*)(nBv + bbase + nj * 1024 + au0);
        bF[nj][1] = *(const bf16x8*)(nBv + bbase + nj * 1024 + au1);
      }
    }
    __builtin_amdgcn_s_barrier();

    if (pre) { sA += 64; sB += 64; }
  }
#undef RDSUB
#undef MFMAPH

#pragma unroll
  for (int mi = 0; mi < MR; ++mi)
#pragma unroll
    for (int nj = 0; nj < 4; ++nj)
#pragma unroll
      for (int e = 0; e < 4; ++e) {
        int row = m0 + wr * 16 + mi * 32 + fq * 4 + e;
        int col = colbase + n0 + wc * 64 + nj * 16 + fr;
        float v = acc[mi][nj][e];
        if (F32OUT) {
          Cf[(size_t)row * ldc + col] = v;
        } else {
          v = v > 0.0f ? v : 0.0f;
          Ch[(size_t)row * ldc + col] = f2bf(v);
        }
      }
}

// ==== 256x256 half-tile-staggered pipelined GEMM (layer 2, f32 out) ====
// R10 fix: vmcnt is PER-WAVE — a wait only covers the executing wave's loads.
// Cross-wave rule: every LDS read of staged data needs wait -> BARRIER -> read.
// Waits: prologue vmcnt(8)+bar; ph0 vmcnt(6) (protects ph1 B1-read & ph2
// A1-read across ph0 barrier); ph3 vmcnt(8) (protects next tile ph0 reads).
// Epilogue: T-2 ph3 vmcnt(4); T-1 ph0 vmcnt(0). FIFO-enumerated.
__global__ __launch_bounds__(512, 2) void gemm256p(
    const ushort* __restrict__ Ag, const ushort* __restrict__ Bg,
    float* __restrict__ Cf, int K, int ldc, int colbase, int mtiles) {
  __shared__ alignas(16) ushort lds[2 * 32768];  // 128 KiB
  const int tid = threadIdx.x;
  const int lane = tid & 63, w = tid >> 6;
  const int wr = w >> 2, wc = w & 3;
  const int fr = lane & 15, fq = lane >> 4, l7 = lane & 7;

  const int nwg = (int)gridDim.x, bid = (int)blockIdx.x;
  const int q8 = nwg >> 3, r8 = nwg & 7;
  const int xcd = bid & 7, ix = bid >> 3;
  const int swz = (xcd < r8 ? xcd * (q8 + 1) : r8 * (q8 + 1) + (xcd - r8) * q8) + ix;
  const int m0 = (swz % mtiles) * 256;
  const int n0 = (swz / mtiles) * 256;

  const int rowq = tid >> 3;
  const int cswz = ((tid & 7) ^ (rowq & 7)) * 8;
  const ushort* sA = Ag + (size_t)(m0 + rowq) * K + cswz;
  const int rB1 = ((rowq >> 5) << 6) + (rowq & 31);
  const ushort* sB = Bg + (size_t)(n0 + rB1) * K + cswz;
  const size_t qstep = (size_t)64 * (size_t)K;
  const size_t Ksz = (size_t)K;

  const int au0 = ((0 * 4 + fq) ^ l7) * 8;
  const int au1 = ((1 * 4 + fq) ^ l7) * 8;
  const int abase = (wr * 16 + fr) * 64;
  const int bbase2 = (wc * 32 + fr) * 64;

  f32x4 acc[8][4] = {};
  bf16x8 aH[4][2], bH0[2][2], bH1[2][2];

#define STA(bufb, h, g, kt)                                             \
  load_lds16(sA + (size_t)((h) * 2 + (g)) * qstep + (size_t)(kt) * 64,  \
             (char*)&lds[(bufb) * 32768 + (h) * 8192 + (g) * 4096 + tid * 8]);
#define STB(bufb, h, g, kt)                                             \
  load_lds16(sB + (size_t)((g) * 128 + (h) * 32) * Ksz + (size_t)(kt) * 64, \
             (char*)&lds[(bufb) * 32768 + 16384 + (h) * 8192 + (g) * 4096 + tid * 8]);
#define RDA(bufb, miH)                                                  \
  _Pragma("unroll")                                                     \
  for (int mi2 = 0; mi2 < 4; ++mi2) {                                   \
    aH[mi2][0] = *(const bf16x8*)&lds[(bufb) * 32768 + ((miH) * 4 + mi2) * 2048 + abase + au0]; \
    aH[mi2][1] = *(const bf16x8*)&lds[(bufb) * 32768 + ((miH) * 4 + mi2) * 2048 + abase + au1]; \
  }
#define RDB(bufb, njH, dst)                                             \
  _Pragma("unroll")                                                     \
  for (int j1 = 0; j1 < 2; ++j1) {                                      \
    dst[j1][0] = *(const bf16x8*)&lds[(bufb) * 32768 + 16384 + (njH) * 8192 + bbase2 + j1 * 1024 + au0]; \
    dst[j1][1] = *(const bf16x8*)&lds[(bufb) * 32768 + 16384 + (njH) * 8192 + bbase2 + j1 * 1024 + au1]; \
  }
#define MF(miH, njH, bArr)                                              \
  __builtin_amdgcn_s_setprio(1);                                        \
  _Pragma("unroll")                                                     \
  for (int kk = 0; kk < 2; ++kk) {                                      \
    _Pragma("unroll")                                                   \
    for (int mi2 = 0; mi2 < 4; ++mi2) {                                 \
      _Pragma("unroll")                                                 \
      for (int j1 = 0; j1 < 2; ++j1)                                    \
        acc[(miH) * 4 + mi2][(njH) * 2 + j1] = __builtin_amdgcn_mfma_f32_16x16x32_bf16( \
            aH[mi2][kk], bArr[j1][kk], acc[(miH) * 4 + mi2][(njH) * 2 + j1], 0, 0, 0); \
    }                                                                   \
  }                                                                     \
  __builtin_amdgcn_s_setprio(0);

  // prologue (FIFO): A0(0) B0(0) A1(0) B1(0) A0(1) B0(1) = 12 gloads
  STA(0, 0, 0, 0); STA(0, 0, 1, 0);
  STB(0, 0, 0, 0); STB(0, 0, 1, 0);
  STA(0, 1, 0, 0); STA(0, 1, 1, 0);
  STB(0, 1, 0, 0); STB(0, 1, 1, 0);
  STA(1, 0, 0, 1); STA(1, 0, 1, 1);
  STB(1, 0, 0, 1); STB(1, 0, 1, 1);
  waitvm<8>();                      // A0(0),B0(0) landed (own wave)
  __builtin_amdgcn_s_barrier();     // ...and all waves' (cross-wave rule)

  const int T = K >> 6;
#pragma unroll 1
  for (int t = 0; t < T; ++t) {
    const int b = t & 1, nb = b ^ 1;
    const bool p1 = (t + 1 < T), p2 = (t + 2 < T);

    // ph0: read A0,B0 (protected by prev ph3 wait + barriers); stage A1(t+1);
    //      wait for A1(t),B1(t) before the barrier (protects ph1/ph2 reads)
    RDA(b, 0); RDB(b, 0, bH0);
    if (p1) { STA(nb, 1, 0, t + 1); STA(nb, 1, 1, t + 1); waitvm<6>(); }
    else    { waitvm<0>(); }
    __builtin_amdgcn_s_barrier();
    MF(0, 0, bH0);
    __builtin_amdgcn_s_barrier();

    // ph1: read B1 (protected); stage B1(t+1)
    RDB(b, 1, bH1);
    if (p1) { STB(nb, 1, 0, t + 1); STB(nb, 1, 1, t + 1); }
    __builtin_amdgcn_s_barrier();
    MF(0, 1, bH1);
    __builtin_amdgcn_s_barrier();

    // ph2: read A1 (protected); stage A0(t+2) into CURRENT buf (slot idle)
    RDA(b, 1);
    if (p2) { STA(b, 0, 0, t + 2); STA(b, 0, 1, t + 2); }
    __builtin_amdgcn_s_barrier();
    MF(1, 0, bH0);
    __builtin_amdgcn_s_barrier();

    // ph3: stage B0(t+2); wait for A0(t+1),B0(t+1) before barrier
    if (p2)      { STB(b, 0, 0, t + 2); STB(b, 0, 1, t + 2); waitvm<8>(); }
    else if (p1) { waitvm<4>(); }
    __builtin_amdgcn_s_barrier();
    MF(1, 1, bH1);
    __builtin_amdgcn_s_barrier();
  }
#undef STA
#undef STB
#undef RDA
#undef RDB
#undef MF

  // epilogue: C/D map col=lane&15, row=(lane>>4)*4+e (m89)
#pragma unroll
  for (int mi = 0; mi < 8; ++mi)
#pragma unroll
    for (int nj = 0; nj < 4; ++nj)
#pragma unroll
      for (int e = 0; e < 4; ++e) {
        int row = m0 + wr * 16 + mi * 32 + fq * 4 + e;
        int col = colbase + n0 + wc * 64 + nj * 16 + fr;
        Cf[(size_t)row * ldc + col] = acc[mi][nj][e];
      }
}

// run one layer: LDS-staged mat (one launch) + gemm per N-chunk
template <int A, int B, int CC, int M, int K, int BM, bool F32OUT, bool PIPE>
static void run_layer256(const ushort* Ain, const float* tbl, ushort* hOut, float* fOut,
                         int N, int ldc, ushort* wb, size_t avail, hipStream_t stream) {
  constexpr int SL = 1 << 15;
  constexpr int NSUB = M / SL;
  const int bps = (NSUB >= 256) ? 1 : (256 / NSUB);
  long ncmax = (long)(avail / (size_t)((size_t)K * 2));
  ncmax = (ncmax / 256) * 256;
  if (ncmax > N) ncmax = N;
  if (ncmax < 256) ncmax = 256;
  const int mtiles = 2048 / BM;
  for (int n0 = 0; n0 < N; n0 += (int)ncmax) {
    int nc = (N - n0 < (int)ncmax) ? (N - n0) : (int)ncmax;
    hipLaunchKernelGGL((mat_lds_kernel<A, B, CC, M, K, SL>),
                       dim3((unsigned)(NSUB * bps)), dim3(512), 0, stream,
                       tbl, wb, n0, nc, bps);
    dim3 g((unsigned)((nc / 256) * mtiles));
    if (PIPE)
      hipLaunchKernelGGL(gemm256p, g, dim3(512), 0, stream,
                         Ain, wb, fOut, K, ldc, n0, mtiles);
    else
      hipLaunchKernelGGL((gemm256<BM, F32OUT>), g, dim3(512), 0, stream,
                         Ain, wb, fOut, hOut, K, ldc, n0, mtiles);
  }
}

extern "C" void kernel_launch(void* const* d_in, const int* in_sizes, int n_in,
                              void* d_out, int out_size, void* d_ws, size_t ws_size,
                              hipStream_t stream) {
  const float* x   = (const float*)d_in[0];
  const float* hw0 = (const float*)d_in[1];
  const float* hw1 = (const float*)d_in[2];
  const float* hw2 = (const float*)d_in[3];
  float* out = (float*)d_out;
  uint8_t* ws = (uint8_t*)d_ws;

  ushort* xb = (ushort*)(ws + 0);                     // 2048x1024 bf16  (4 MB)
  ushort* h1 = (ushort*)(ws + ((size_t)4 << 20));     // 2048x4096 bf16 (16 MB)
  ushort* h2 = (ushort*)(ws + ((size_t)20 << 20));    // 2048x4096 bf16 (16 MB)
  ushort* wb = (ushort*)(ws + ((size_t)36 << 20));    // W^T chunk buffer
  size_t avail = ws_size > ((size_t)36 << 20) ? ws_size - ((size_t)36 << 20)
                                              : (size_t)(128 * 4096 * 2);

  hipLaunchKernelGGL(cvt_bf16_kernel, dim3(1024), dim3(256), 0, stream,
                     (const float4*)x, (ushort4*)xb, 2048 * 1024 / 4);

  // layer 0: [2048,1024] @ [1024,4096], relu -> h1 (bf16)  [BM=128 4-phase]
  run_layer256<9973, 31013, 557, 1 << 20, 1024, 128, false, false>(
      xb, hw0, h1, nullptr, 4096, 4096, wb, avail, stream);
  // layer 1: [2048,4096] @ [4096,4096], relu -> h2 (bf16)  [BM=128 4-phase]
  run_layer256<10007, 31019, 563, 1 << 20, 4096, 128, false, false>(
      h1, hw1, h2, nullptr, 4096, 4096, wb, avail, stream);
  // layer 2: [2048,4096] @ [4096,32000] -> out (f32)       [256^2 staggered]
  run_layer256<10039, 31039, 569, 1 << 22, 4096, 256, true, true>(
      h2, hw2, nullptr, out, 32000, 32000, wb, avail, stream);
}